// Round 1
// baseline (494.540 us; speedup 1.0000x reference)
//
#include <hip/hip_runtime.h>

namespace {

constexpr float ALPHA = 0.2f;
constexpr float TAU   = 0.25f;
constexpr int   NITER = 10;
constexpr float EPSV  = 1e-12f;

constexpr int H = 256, W = 256;
constexpr int TILE = 64;
constexpr int HALO = 10;             // = NITER dependency radius
constexpr int RG   = TILE + 2*HALO;  // 84 region rows/cols
constexpr int QR   = RG / 4;         // 21 quads per region row
constexpr int NQ   = RG * QR;        // 1764 quads per region
constexpr int NT   = 1024;           // threads per block

// LDS layout: u | px | py contiguous (each NQ*4 floats). Edge neighbor reads
// that fall off one array land inside the next (bounded garbage, never used
// by the valid shrinking region).
__launch_bounds__(NT)
__global__ void tv_lrelu_kernel(const float* __restrict__ z,
                                const float* __restrict__ lam_p,
                                float* __restrict__ out) {
  __shared__ __align__(16) float lds[3 * NQ * 4 + 4];
  float* const su  = lds;
  float* const spx = lds + NQ * 4;
  float* const spy = lds + 2 * NQ * 4;

  const float lam_c = fminf(fmaxf(lam_p[0], 0.0f), 1.0f);
  const float cg = lam_c * TAU;   // grad step:  p += lam*tau * grad(u)
  // div step uses lam_c directly: u = lrelu(z + lam_c * div(p))

  const int b   = blockIdx.x;
  const int img = b >> 4;          // 16 tiles (4x4) per image
  const int tr  = (b >> 2) & 3;
  const int tc  = b & 3;
  const long base = (long)img * (H * W);
  const int r0 = tr * TILE - HALO; // global row of region-local row 0
  const int c0 = tc * TILE - HALO;
  const int tid = threadIdx.x;

  // Per-thread: 2 quads (4 consecutive pixels each). Own u/px/py/z live in
  // registers; LDS is only for cross-thread neighbor exchange.
  float uq[2][4], pxq[2][4], pyq[2][4], zq[2][4];
  int gi_[2], gj_[2], qe[2];
  bool act[2];

#pragma unroll
  for (int s = 0; s < 2; ++s) {
    int q = tid + s * NT;
    act[s] = (q < NQ);
    if (q >= NQ) q = 0;                 // inactive lanes alias quad 0 (reads only)
    const int row = q / QR;
    const int qc  = q - row * QR;
    qe[s] = q * 4;                      // element offset; byte offset = q*16 (linear, conflict-free)
    const int gi = r0 + row;
    const int gj = c0 + qc * 4;
    gi_[s] = gi;
    gj_[s] = gj;
    const bool rin = (gi >= 0) & (gi < H);
    const float* zp = z + base + (long)gi * W + gj;
#pragma unroll
    for (int k = 0; k < 4; ++k) {
      const int gjk = gj + k;
      const float zv = (rin & (gjk >= 0) & (gjk < W)) ? zp[k] : 0.0f;
      zq[s][k]  = zv;
      uq[s][k]  = fmaxf(zv, ALPHA * zv);  // leaky_relu(z)
      pxq[s][k] = 0.0f;
      pyq[s][k] = 0.0f;
    }
    if (act[s]) {
      *reinterpret_cast<float4*>(&su[qe[s]]) =
          make_float4(uq[s][0], uq[s][1], uq[s][2], uq[s][3]);
    }
  }
  __syncthreads();

  for (int t = 0; t < NITER; ++t) {
    // ---- phase 1: p += cg*grad(u); project onto unit ball ----
#pragma unroll
    for (int s = 0; s < 2; ++s) {
      const float4 udn = *reinterpret_cast<const float4*>(&su[qe[s] + RG]); // row+1
      const float4 urt = *reinterpret_cast<const float4*>(&su[qe[s] + 4]);  // right quad
      const float un[4] = {uq[s][1], uq[s][2], uq[s][3], urt.x};            // u(i, j+1)
      const float ud[4] = {udn.x, udn.y, udn.z, udn.w};                     // u(i+1, j)
      const bool gy_ok = (gi_[s] < H - 1);
#pragma unroll
      for (int k = 0; k < 4; ++k) {
        const bool gx_ok = (gj_[s] + k < W - 1);
        const float gx = gx_ok ? (un[k] - uq[s][k]) : 0.0f;
        const float gy = gy_ok ? (ud[k] - uq[s][k]) : 0.0f;
        const float px = fmaf(cg, gx, pxq[s][k]);
        const float py = fmaf(cg, gy, pyq[s][k]);
        const float n2 = fmaf(px, px, fmaf(py, py, EPSV));
        const float rn = rsqrtf(n2);           // 1/sqrt(n2)
        const float sc = fminf(rn, 1.0f);      // 1/max(norm,1)
        pxq[s][k] = px * sc;
        pyq[s][k] = py * sc;
      }
      if (act[s]) {
        *reinterpret_cast<float4*>(&spx[qe[s]]) =
            make_float4(pxq[s][0], pxq[s][1], pxq[s][2], pxq[s][3]);
        *reinterpret_cast<float4*>(&spy[qe[s]]) =
            make_float4(pyq[s][0], pyq[s][1], pyq[s][2], pyq[s][3]);
      }
    }
    __syncthreads();

    // ---- phase 2: u = lrelu(z + lam * div(p)) ----
#pragma unroll
    for (int s = 0; s < 2; ++s) {
      const float4 pxl4 = *reinterpret_cast<const float4*>(&spx[qe[s] - 4]);  // left quad
      const float4 pyu4 = *reinterpret_cast<const float4*>(&spy[qe[s] - RG]); // row-1
      const float pxl[4] = {pxl4.w, pxq[s][0], pxq[s][1], pxq[s][2]};         // px(i, j-1)
      const float pyu[4] = {pyu4.x, pyu4.y, pyu4.z, pyu4.w};                  // py(i-1, j)
      const bool dy_ok = (gi_[s] > 0);
#pragma unroll
      for (int k = 0; k < 4; ++k) {
        const bool dx_ok = (gj_[s] + k > 0);
        const float dx = pxq[s][k] - (dx_ok ? pxl[k] : 0.0f);
        const float dy = pyq[s][k] - (dy_ok ? pyu[k] : 0.0f);
        const float a  = fmaf(lam_c, dx + dy, zq[s][k]);
        uq[s][k] = fmaxf(a, ALPHA * a);
      }
      if (act[s]) {
        *reinterpret_cast<float4*>(&su[qe[s]]) =
            make_float4(uq[s][0], uq[s][1], uq[s][2], uq[s][3]);
      }
    }
    __syncthreads();
  }

  // ---- write center 64x64 tile: one output quad per thread ----
  {
    const int orow = tid >> 4;       // 0..63
    const int oq   = tid & 15;       // 0..15
    const int li = HALO + orow;
    const int lj = HALO + oq * 4;
    const float* src = &su[li * RG + lj];
    const float4 v = make_float4(src[0], src[1], src[2], src[3]);
    float* dst = out + base + (long)(tr * TILE + orow) * W + (tc * TILE + oq * 4);
    *reinterpret_cast<float4*>(dst) = v;
  }
}

} // namespace

extern "C" void kernel_launch(void* const* d_in, const int* in_sizes, int n_in,
                              void* d_out, int out_size, void* d_ws, size_t ws_size,
                              hipStream_t stream) {
  const float* z   = (const float*)d_in[0];
  const float* lam = (const float*)d_in[1];
  float* out = (float*)d_out;

  const int n_img = in_sizes[0] / (H * W);    // 512 for (8,64,256,256)
  const int n_blocks = n_img * 16;            // 4x4 tiles per image

  tv_lrelu_kernel<<<n_blocks, NT, 0, stream>>>(z, lam, out);
}